// Round 2
// baseline (51.130 us; speedup 1.0000x reference)
//
#include <hip/hip_runtime.h>

#define D_MODEL 2048
#define D4 (D_MODEL / 4)   // 512 float4 per row

// One wave computes 2 adjacent rows' 3 dot products over D=2048 (16 float4
// loads in flight), reduces via 64-lane butterfly, then lanes 0..2 apply the
// closed-form diffusion blend and write. W (24 KB) staged to LDS per block.
__global__ __launch_bounds__(256) void diff_coord_kernel(
    const float* __restrict__ latent,
    const float* __restrict__ W,
    const float* __restrict__ b,
    const float* __restrict__ noise,
    const int*   __restrict__ tsteps,
    float*       __restrict__ out,
    int nrows)
{
    __shared__ float4 wlds[3][D4];   // 24 KB

    const float4* W4 = reinterpret_cast<const float4*>(W);
    for (int i = threadIdx.x; i < 3 * D4; i += 256) {
        wlds[i / D4][i % D4] = W4[i];
    }
    __syncthreads();

    const int wid  = threadIdx.x >> 6;
    const int lane = threadIdx.x & 63;
    const int T    = tsteps[0];

    // x_{k+1} = a*x_k + (1-a)*c with fixed point c  =>  x_T = p*x_0 + (1-p)*c,
    // p = prod_{t=1..T} t/T. Rounding delta vs the unrolled loop ~1e-6.
    float p = 1.0f;
    for (int t = 1; t <= T; ++t) p *= (float)t / (float)T;
    const float q = 1.0f - p;

    const float bias = (lane < 3) ? b[lane] : 0.0f;

    const int wave_stride = gridDim.x * 4;        // total waves in grid
    for (int base = (blockIdx.x * 4 + wid) * 2; base < nrows;
         base += wave_stride * 2) {
        const int  rowA = base;
        const int  rowB = base + 1;
        const bool hasB = (rowB < nrows);          // wave-uniform

        // Early noise loads: issued before the latent FMA loop so their
        // latency hides under the latent-load wait (they were a dependent
        // post-reduction stall before).
        const float nzA = (lane < 3) ? noise[(size_t)rowA * 3 + lane] : 0.0f;
        const float nzB = (hasB && lane < 3) ? noise[(size_t)rowB * 3 + lane] : 0.0f;

        const float4* lA = reinterpret_cast<const float4*>(latent) + (size_t)rowA * D4;
        const float4* lB = reinterpret_cast<const float4*>(latent) + (size_t)rowB * D4;

        float a0 = 0.f, a1 = 0.f, a2 = 0.f;       // row A accumulators
        float c0 = 0.f, c1 = 0.f, c2 = 0.f;       // row B accumulators

        if (hasB) {
            #pragma unroll
            for (int k = 0; k < D4 / 64; ++k) {   // 8 iterations, 16 loads in flight
                const int j = k * 64 + lane;
                const float4 xA = lA[j];
                const float4 xB = lB[j];
                const float4 w0 = wlds[0][j];
                const float4 w1 = wlds[1][j];
                const float4 w2 = wlds[2][j];
                a0 += xA.x * w0.x + xA.y * w0.y + xA.z * w0.z + xA.w * w0.w;
                a1 += xA.x * w1.x + xA.y * w1.y + xA.z * w1.z + xA.w * w1.w;
                a2 += xA.x * w2.x + xA.y * w2.y + xA.z * w2.z + xA.w * w2.w;
                c0 += xB.x * w0.x + xB.y * w0.y + xB.z * w0.z + xB.w * w0.w;
                c1 += xB.x * w1.x + xB.y * w1.y + xB.z * w1.z + xB.w * w1.w;
                c2 += xB.x * w2.x + xB.y * w2.y + xB.z * w2.z + xB.w * w2.w;
            }
        } else {
            #pragma unroll
            for (int k = 0; k < D4 / 64; ++k) {
                const int j = k * 64 + lane;
                const float4 xA = lA[j];
                const float4 w0 = wlds[0][j];
                const float4 w1 = wlds[1][j];
                const float4 w2 = wlds[2][j];
                a0 += xA.x * w0.x + xA.y * w0.y + xA.z * w0.z + xA.w * w0.w;
                a1 += xA.x * w1.x + xA.y * w1.y + xA.z * w1.z + xA.w * w1.w;
                a2 += xA.x * w2.x + xA.y * w2.y + xA.z * w2.z + xA.w * w2.w;
            }
        }

        // 64-lane butterfly reduction.
        #pragma unroll
        for (int off = 32; off >= 1; off >>= 1) {
            a0 += __shfl_xor(a0, off);
            a1 += __shfl_xor(a1, off);
            a2 += __shfl_xor(a2, off);
            c0 += __shfl_xor(c0, off);
            c1 += __shfl_xor(c1, off);
            c2 += __shfl_xor(c2, off);
        }

        if (lane < 3) {
            const float cA = (lane == 0 ? a0 : (lane == 1 ? a1 : a2)) + bias;
            out[(size_t)rowA * 3 + lane] = p * nzA + q * cA;
            if (hasB) {
                const float cB = (lane == 0 ? c0 : (lane == 1 ? c1 : c2)) + bias;
                out[(size_t)rowB * 3 + lane] = p * nzB + q * cB;
            }
        }
    }
}

extern "C" void kernel_launch(void* const* d_in, const int* in_sizes, int n_in,
                              void* d_out, int out_size, void* d_ws, size_t ws_size,
                              hipStream_t stream) {
    const float* latent = (const float*)d_in[0];
    const float* W      = (const float*)d_in[1];
    const float* b      = (const float*)d_in[2];
    const float* noise  = (const float*)d_in[3];
    const int*   tsteps = (const int*)d_in[4];
    float* out = (float*)d_out;

    const int nrows = in_sizes[0] / D_MODEL;   // B*S = 32768

    // 2048 blocks x 4 waves x 2 rows/iter = 16384 rows per sweep, 2 sweeps.
    diff_coord_kernel<<<2048, 256, 0, stream>>>(latent, W, b, noise, tsteps,
                                                out, nrows);
}